// Round 5
// baseline (11517.737 us; speedup 1.0000x reference)
//
#include <hip/hip_runtime.h>
#include <hip/hip_bf16.h>
#include <cstdint>
#include <cstddef>

// NaryTreeLSTM: ONE persistent kernel for the whole 16-level tree.
// Grid = 1024 blocks (4/CU on 256 CUs, co-resident by construction:
// 20KB LDS, __launch_bounds__(256,4) caps VGPR at 128 -> 4 waves/SIMD).
// Hierarchical grid barrier (32 groups x 32 blocks, monotonic counters,
// agent-scope atomics) between levels. Phase 0 packs weights + converts emb.
//
// 3-phase K-split per internal node (no structural zeros, W_f x once):
//   phase 0: k = x,   slots {W_i, W_o, W_u, W_f}
//   phase 1: k = h_l, slots {U_i0, U_o0, U_u0, U_f0}
//   phase 2: k = h_r, slots {U_i1, U_o1, U_u1, U_f1}
// i,o,u accumulate across phases; f kept per-phase:
//   f_l = sig(fx+f1+b_f), f_r = sig(fx+f2+b_f).
// Leaf (level 15): 1 phase, 3 slots, c = i*u.
//
// Tile: 64 rows x 64 d x slots; 4 waves, wave w owns d-slice w*16 (epilogue
// wave-local). Per level: ntiles = 4 * ceil(n/64), grid-strided.

typedef __attribute__((ext_vector_type(8))) __bf16 bf16x8;
typedef __attribute__((ext_vector_type(4))) float floatx4;

#define NBLK 1024

__device__ __forceinline__ float sigf(float x) { return 1.0f / (1.0f + __expf(-x)); }

__device__ __forceinline__ void load_lds16(const void* g, void* l) {
    __builtin_amdgcn_global_load_lds(
        (const __attribute__((address_space(1))) unsigned int*)g,
        (__attribute__((address_space(3))) unsigned int*)l, 16, 0, 0);
}

// --- hierarchical grid barrier (monotonic, no resets) ---------------------
// bar layout (unsigned words): group g: cnt at g*32, gen at g*32+16;
// root: cnt at 1024, gen at 1024+16.  32 groups x 32 blocks, grid == 1024.
__device__ __forceinline__ void grid_sync(unsigned* bar, int bid, unsigned barnum)
{
    __syncthreads();
    if (threadIdx.x == 0) {
        const int g = bid >> 5;
        unsigned* gcnt = bar + g * 32;
        unsigned* ggen = bar + g * 32 + 16;
        unsigned* rcnt = bar + NBLK;
        unsigned* rgen = bar + NBLK + 16;
        unsigned v = __hip_atomic_fetch_add(gcnt, 1, __ATOMIC_RELEASE, __HIP_MEMORY_SCOPE_AGENT) + 1;
        if (v == barnum * 32u) {
            // last of group -> arrive at root
            unsigned r = __hip_atomic_fetch_add(rcnt, 1, __ATOMIC_ACQ_REL, __HIP_MEMORY_SCOPE_AGENT) + 1;
            if (r == barnum * 32u) {
                __hip_atomic_fetch_add(rgen, 1, __ATOMIC_RELEASE, __HIP_MEMORY_SCOPE_AGENT);
            } else {
                while (__hip_atomic_load(rgen, __ATOMIC_ACQUIRE, __HIP_MEMORY_SCOPE_AGENT) < barnum)
                    __builtin_amdgcn_s_sleep(1);
            }
            __hip_atomic_fetch_add(ggen, 1, __ATOMIC_RELEASE, __HIP_MEMORY_SCOPE_AGENT);
        } else {
            while (__hip_atomic_load(ggen, __ATOMIC_ACQUIRE, __HIP_MEMORY_SCOPE_AGENT) < barnum)
                __builtin_amdgcn_s_sleep(1);
        }
    }
    __syncthreads();
}

__global__ void init_bar(unsigned* bar)
{
    for (int i = threadIdx.x; i < NBLK + 32; i += 256) bar[i] = 0u;
}

// --- fused tile: GEMM + LSTM cell, wave-local epilogue --------------------
template<int NS, int NP>
__device__ __forceinline__ void do_tile(
    const __hip_bfloat16* __restrict__ embX,   // [.][256]
    const __hip_bfloat16* __restrict__ hprev,  // [.][512]
    const float* __restrict__ cprev,           // [.][512]
    const __hip_bfloat16* __restrict__ Wpack,  // [12][256][256]
    const float* __restrict__ biasv,           // [4][256]
    __hip_bfloat16* __restrict__ hout,         // [.][256]
    float* __restrict__ cout,                  // [.][256]
    int M, int bm0, int dchunk,
    __hip_bfloat16* sA, __hip_bfloat16* sB)
{
    const int t = threadIdx.x;
    const int lane = t & 63;
    const int w = t >> 6;
    const int lrow = lane & 15;
    const int q = lane >> 4;

    floatx4 accS[3][4];
    floatx4 accF[NP][4];
    #pragma unroll
    for (int s = 0; s < 3; ++s)
        #pragma unroll
        for (int mt = 0; mt < 4; ++mt) accS[s][mt] = (floatx4){0.f, 0.f, 0.f, 0.f};
    #pragma unroll
    for (int p = 0; p < NP; ++p)
        #pragma unroll
        for (int mt = 0; mt < 4; ++mt) accF[p][mt] = (floatx4){0.f, 0.f, 0.f, 0.f};

    #pragma unroll
    for (int p = 0; p < NP; ++p) {
        const __hip_bfloat16* Abase = (p == 0) ? embX : hprev;
        const int astride = (p == 0) ? 256 : 512;
        const int aoff = (p == 0) ? 0 : (p - 1) * 256;
        for (int kk = 0; kk < 8; ++kk) {
            const int k0 = kk * 32;
            {
                int r = t >> 2, kc = t & 3;
                load_lds16(Abase + (size_t)(bm0 + r) * astride + aoff + k0 + kc * 8,
                           &sA[t * 8]);
            }
            #pragma unroll
            for (int rep = 0; rep < NS; ++rep) {
                int cid = rep * 256 + t;
                int row = cid >> 2, kc = cid & 3;
                int s = row >> 6, r = row & 63;
                load_lds16(Wpack + (size_t)((p * 4 + s) * 256 + dchunk * 64 + r) * 256 + k0 + kc * 8,
                           &sB[cid * 8]);
            }
            __syncthreads();

            bf16x8 af[4];
            #pragma unroll
            for (int mt = 0; mt < 4; ++mt)
                af[mt] = *(const bf16x8*)&sA[(mt * 16 + lrow) * 32 + q * 8];
            #pragma unroll
            for (int s = 0; s < NS; ++s) {
                bf16x8 bfrag = *(const bf16x8*)&sB[(s * 64 + w * 16 + lrow) * 32 + q * 8];
                if (s < 3) {
                    #pragma unroll
                    for (int mt = 0; mt < 4; ++mt)
                        accS[s][mt] = __builtin_amdgcn_mfma_f32_16x16x32_bf16(af[mt], bfrag, accS[s][mt], 0, 0, 0);
                } else {
                    #pragma unroll
                    for (int mt = 0; mt < 4; ++mt)
                        accF[p][mt] = __builtin_amdgcn_mfma_f32_16x16x32_bf16(af[mt], bfrag, accF[p][mt], 0, 0, 0);
                }
            }
            __syncthreads();
        }
    }

    // Epilogue. C/D layout: col=lane&15, row=q*4+reg.
    const int d = dchunk * 64 + w * 16 + lrow;
    const float bI = biasv[d];
    const float bO = biasv[256 + d];
    const float bU = biasv[512 + d];
    const float bF = (NS == 4) ? biasv[768 + d] : 0.0f;
    #pragma unroll
    for (int mt = 0; mt < 4; ++mt) {
        #pragma unroll
        for (int rr = 0; rr < 4; ++rr) {
            const int m = bm0 + mt * 16 + q * 4 + rr;
            if (m >= M) continue;
            float iv = sigf(accS[0][mt][rr] + bI);
            float ov = sigf(accS[1][mt][rr] + bO);
            float uv = tanhf(accS[2][mt][rr] + bU);
            float c;
            if (NS == 4) {
                float fx = accF[0][mt][rr];
                float fl = sigf(fx + accF[NP >= 2 ? 1 : 0][mt][rr] + bF);
                float fr = sigf(fx + accF[NP >= 3 ? 2 : 0][mt][rr] + bF);
                c = iv * uv + fl * cprev[(size_t)m * 512 + d]
                            + fr * cprev[(size_t)m * 512 + 256 + d];
            } else {
                c = iv * uv;
            }
            cout[(size_t)m * 256 + d] = c;
            hout[(size_t)m * 256 + d] = __float2bfloat16(ov * tanhf(c));
        }
    }
}

__global__ __launch_bounds__(256, 4) void tree_lstm_all(
    const float* __restrict__ emb,
    const float* __restrict__ Wi, const float* __restrict__ bi, const float* __restrict__ Ui,
    const float* __restrict__ Wo, const float* __restrict__ bo, const float* __restrict__ Uo,
    const float* __restrict__ Wu, const float* __restrict__ bu, const float* __restrict__ Uu,
    const float* __restrict__ Wf, const float* __restrict__ bf, const float* __restrict__ Uf,
    __hip_bfloat16* __restrict__ Wpack, float* __restrict__ biasv,
    __hip_bfloat16* __restrict__ embB,
    __hip_bfloat16* __restrict__ hbuf, float* __restrict__ cbuf,
    unsigned* __restrict__ bar, float* __restrict__ out)
{
    __shared__ __hip_bfloat16 sA[64 * 32];
    __shared__ __hip_bfloat16 sB[4 * 64 * 32];
    const int bid = blockIdx.x;
    const int gid = bid * 256 + threadIdx.x;
    unsigned barnum = 0;

    // ---- phase 0: pack weights (bf16) + bias, convert emb -> bf16 ----
    {
        const float* tbl[12] = {Wi, Wo, Wu, Wf, Ui, Uo, Uu, Uf,
                                Ui + 65536, Uo + 65536, Uu + 65536, Uf + 65536};
        for (int i = gid; i < 12 * 65536; i += NBLK * 256) {
            int m = i >> 16, rem = i & 65535;
            Wpack[i] = __float2bfloat16(tbl[m][rem]);
        }
        if (gid < 1024) {
            const float* bt[4] = {bi, bo, bu, bf};
            biasv[gid] = bt[gid >> 8][gid & 255];
        }
        const int n4 = 65535 * 256 / 4;
        for (int i = gid; i < n4; i += NBLK * 256) {
            float4 v = ((const float4*)emb)[i];
            __hip_bfloat16 tmp[4];
            tmp[0] = __float2bfloat16(v.x);
            tmp[1] = __float2bfloat16(v.y);
            tmp[2] = __float2bfloat16(v.z);
            tmp[3] = __float2bfloat16(v.w);
            *(ushort4*)(embB + (size_t)i * 4) = *(const ushort4*)tmp;
        }
    }
    grid_sync(bar, bid, ++barnum);

    // ---- levels 15 (leaf) .. 0, grid-stride over 64x64 tiles ----
    for (int l = 15; l >= 0; --l) {
        const int n = 1 << l;
        const int start = n - 1;
        const int startc = 2 * n - 1;
        const int ntiles = ((n + 63) >> 6) * 4;
        for (int tile = bid; tile < ntiles; tile += NBLK) {
            const int bm0 = (tile >> 2) * 64;
            const int dchunk = tile & 3;
            if (l == 15)
                do_tile<3, 1>(embB + (size_t)start * 256, nullptr, nullptr,
                              Wpack, biasv,
                              hbuf + (size_t)start * 256, cbuf + (size_t)start * 256,
                              n, bm0, dchunk, sA, sB);
            else
                do_tile<4, 3>(embB + (size_t)start * 256,
                              hbuf + (size_t)startc * 256, cbuf + (size_t)startc * 256,
                              Wpack, biasv,
                              hbuf + (size_t)start * 256, cbuf + (size_t)start * 256,
                              n, bm0, dchunk, sA, sB);
        }
        grid_sync(bar, bid, ++barnum);
    }

    // ---- write root output ----
    if (bid == 0) {
        int t = threadIdx.x;
        out[t] = __bfloat162float(hbuf[t]);
        out[256 + t] = cbuf[t];
    }
}

extern "C" void kernel_launch(void* const* d_in, const int* in_sizes, int n_in,
                              void* d_out, int out_size, void* d_ws, size_t ws_size,
                              hipStream_t stream)
{
    const float* emb = (const float*)d_in[0];
    const float* Wi  = (const float*)d_in[1];
    const float* bi  = (const float*)d_in[2];
    const float* Ui  = (const float*)d_in[3];
    const float* Wo  = (const float*)d_in[4];
    const float* bo  = (const float*)d_in[5];
    const float* Uo  = (const float*)d_in[6];
    const float* Wu  = (const float*)d_in[7];
    const float* bu  = (const float*)d_in[8];
    const float* Uu  = (const float*)d_in[9];
    const float* Wf  = (const float*)d_in[10];
    const float* bf  = (const float*)d_in[11];
    const float* Uf  = (const float*)d_in[12];

    char* p = (char*)d_ws;
    __hip_bfloat16* Wpack = (__hip_bfloat16*)p;  p += (size_t)12 * 256 * 256 * 2;
    float* biasv          = (float*)p;           p += (size_t)4 * 256 * 4;
    __hip_bfloat16* embB  = (__hip_bfloat16*)p;  p += (size_t)65535 * 256 * 2;
    __hip_bfloat16* hbuf  = (__hip_bfloat16*)p;  p += (size_t)65535 * 256 * 2;
    float* cbuf           = (float*)p;           p += (size_t)65535 * 256 * 4;
    unsigned* bar         = (unsigned*)p;        p += (size_t)(NBLK + 64) * 4;

    init_bar<<<1, 256, 0, stream>>>(bar);
    tree_lstm_all<<<NBLK, 256, 0, stream>>>(
        emb, Wi, bi, Ui, Wo, bo, Uo, Wu, bu, Uu, Wf, bf, Uf,
        Wpack, biasv, embB, hbuf, cbuf, bar, (float*)d_out);
}

// Round 6
// 603.131 us; speedup vs baseline: 19.0966x; 19.0966x over previous
//
#include <hip/hip_runtime.h>
#include <hip/hip_bf16.h>
#include <cstdint>
#include <cstddef>

// NaryTreeLSTM bottom-up:
//  - levels 15..11 (n>=2048): R4's fused LDS-tiled MFMA kernel, one launch each
//  - levels 10..0: ONE 64-block kernel, fragments loaded straight to VGPRs
//    (no LDS / no intra-K syncs), relaxed-spin grid barrier between levels.
//
// 3-phase K-split (no structural zeros, W_f x computed once):
//   p0: k=x   slots {W_i,W_o,W_u,W_f}; p1: k=h_l {U_*0}; p2: k=h_r {U_*1}
// i,o,u accumulate across phases; f per-phase: f_l=sig(fx+f1+bF), f_r=sig(fx+f2+bF).
// Wpack[12][256][256] bf16 (mat = p*4+s), biasv[4][256] fp32.

typedef __attribute__((ext_vector_type(8))) __bf16 bf16x8;
typedef __attribute__((ext_vector_type(4))) float floatx4;

#define TB 64   // tail grid

__device__ __forceinline__ float sigf(float x) { return 1.0f / (1.0f + __expf(-x)); }

__device__ __forceinline__ void load_lds16(const void* g, void* l) {
    __builtin_amdgcn_global_load_lds(
        (const __attribute__((address_space(1))) unsigned int*)g,
        (__attribute__((address_space(3))) unsigned int*)l, 16, 0, 0);
}

__global__ void pack_weights(const float* __restrict__ Wi, const float* __restrict__ bi, const float* __restrict__ Ui,
                             const float* __restrict__ Wo, const float* __restrict__ bo, const float* __restrict__ Uo,
                             const float* __restrict__ Wu, const float* __restrict__ bu, const float* __restrict__ Uu,
                             const float* __restrict__ Wf, const float* __restrict__ bf, const float* __restrict__ Uf,
                             __hip_bfloat16* __restrict__ Wpack, float* __restrict__ biasv)
{
    int m = blockIdx.x;   // 0..11 = p*4+s
    int d = blockIdx.y;   // 0..255
    int k = threadIdx.x;  // 0..255
    const float* tbl[12] = {Wi, Wo, Wu, Wf,
                            Ui, Uo, Uu, Uf,
                            Ui + 65536, Uo + 65536, Uu + 65536, Uf + 65536};
    Wpack[((size_t)m * 256 + d) * 256 + k] = __float2bfloat16(tbl[m][d * 256 + k]);
    if (m < 4 && k == 0) {
        const float* bt[4] = {bi, bo, bu, bf};
        biasv[m * 256 + d] = bt[m][d];
    }
}

__global__ void convert_f32_bf16(const float* __restrict__ in, __hip_bfloat16* __restrict__ out, int n4)
{
    int i = blockIdx.x * 256 + threadIdx.x;
    if (i >= n4) return;
    float4 v = ((const float4*)in)[i];
    __hip_bfloat16 tmp[4];
    tmp[0] = __float2bfloat16(v.x);
    tmp[1] = __float2bfloat16(v.y);
    tmp[2] = __float2bfloat16(v.z);
    tmp[3] = __float2bfloat16(v.w);
    *(ushort4*)(out + (size_t)i * 4) = *(const ushort4*)tmp;
}

// ---- big levels: R4 LDS-tiled fused kernel (unchanged) -------------------
template<int NS, int NP>
__global__ __launch_bounds__(256) void fused_level(
    const __hip_bfloat16* __restrict__ embX,   // [.][256]
    const __hip_bfloat16* __restrict__ hprev,  // [.][512]
    const float* __restrict__ cprev,           // [.][512]
    const __hip_bfloat16* __restrict__ Wpack,  // [12][256][256]
    const float* __restrict__ biasv,           // [4][256]
    __hip_bfloat16* __restrict__ hout,         // [.][256]
    float* __restrict__ cout,                  // [.][256]
    int M)
{
    __shared__ __hip_bfloat16 sA[64 * 32];
    __shared__ __hip_bfloat16 sB[NS * 64 * 32];
    const int t = threadIdx.x;
    const int dchunk = blockIdx.x;
    const int bm0 = blockIdx.y * 64;
    const int lane = t & 63;
    const int w = t >> 6;
    const int lrow = lane & 15;
    const int q = lane >> 4;

    floatx4 accS[3][4];
    floatx4 accF[NP][4];
    #pragma unroll
    for (int s = 0; s < 3; ++s)
        #pragma unroll
        for (int mt = 0; mt < 4; ++mt) accS[s][mt] = (floatx4){0.f, 0.f, 0.f, 0.f};
    #pragma unroll
    for (int p = 0; p < NP; ++p)
        #pragma unroll
        for (int mt = 0; mt < 4; ++mt) accF[p][mt] = (floatx4){0.f, 0.f, 0.f, 0.f};

    #pragma unroll
    for (int p = 0; p < NP; ++p) {
        const __hip_bfloat16* Abase = (p == 0) ? embX : hprev;
        const int astride = (p == 0) ? 256 : 512;
        const int aoff = (p == 0) ? 0 : (p - 1) * 256;
        for (int kk = 0; kk < 8; ++kk) {
            const int k0 = kk * 32;
            {
                int r = t >> 2, kc = t & 3;
                load_lds16(Abase + (size_t)(bm0 + r) * astride + aoff + k0 + kc * 8,
                           &sA[t * 8]);
            }
            #pragma unroll
            for (int rep = 0; rep < NS; ++rep) {
                int cid = rep * 256 + t;
                int row = cid >> 2, kc = cid & 3;
                int s = row >> 6, r = row & 63;
                load_lds16(Wpack + (size_t)((p * 4 + s) * 256 + dchunk * 64 + r) * 256 + k0 + kc * 8,
                           &sB[cid * 8]);
            }
            __syncthreads();

            bf16x8 af[4];
            #pragma unroll
            for (int mt = 0; mt < 4; ++mt)
                af[mt] = *(const bf16x8*)&sA[(mt * 16 + lrow) * 32 + q * 8];
            #pragma unroll
            for (int s = 0; s < NS; ++s) {
                bf16x8 bfrag = *(const bf16x8*)&sB[(s * 64 + w * 16 + lrow) * 32 + q * 8];
                if (s < 3) {
                    #pragma unroll
                    for (int mt = 0; mt < 4; ++mt)
                        accS[s][mt] = __builtin_amdgcn_mfma_f32_16x16x32_bf16(af[mt], bfrag, accS[s][mt], 0, 0, 0);
                } else {
                    #pragma unroll
                    for (int mt = 0; mt < 4; ++mt)
                        accF[p][mt] = __builtin_amdgcn_mfma_f32_16x16x32_bf16(af[mt], bfrag, accF[p][mt], 0, 0, 0);
                }
            }
            __syncthreads();
        }
    }

    const int d = dchunk * 64 + w * 16 + lrow;
    const float bI = biasv[d];
    const float bO = biasv[256 + d];
    const float bU = biasv[512 + d];
    const float bF = (NS == 4) ? biasv[768 + d] : 0.0f;
    #pragma unroll
    for (int mt = 0; mt < 4; ++mt) {
        #pragma unroll
        for (int rr = 0; rr < 4; ++rr) {
            const int m = bm0 + mt * 16 + q * 4 + rr;
            if (m >= M) continue;
            float iv = sigf(accS[0][mt][rr] + bI);
            float ov = sigf(accS[1][mt][rr] + bO);
            float uv = tanhf(accS[2][mt][rr] + bU);
            float c;
            if (NS == 4) {
                float fx = accF[0][mt][rr];
                float fl = sigf(fx + accF[NP >= 2 ? 1 : 0][mt][rr] + bF);
                float fr = sigf(fx + accF[NP >= 3 ? 2 : 0][mt][rr] + bF);
                c = iv * uv + fl * cprev[(size_t)m * 512 + d]
                            + fr * cprev[(size_t)m * 512 + 256 + d];
            } else {
                c = iv * uv;
            }
            cout[(size_t)m * 256 + d] = c;
            hout[(size_t)m * 256 + d] = __float2bfloat16(ov * tanhf(c));
        }
    }
}

// ---- tail: levels 10..0 in one kernel, register-direct fragments ---------
__global__ __launch_bounds__(256) void tail_levels(
    const __hip_bfloat16* __restrict__ embB,
    __hip_bfloat16* __restrict__ hbuf, float* __restrict__ cbuf,
    const __hip_bfloat16* __restrict__ Wpack, const float* __restrict__ biasv,
    unsigned* __restrict__ bar, float* __restrict__ out)
{
    const int bid = blockIdx.x;
    const int t = threadIdx.x;
    const int w = t >> 6;
    const int lane = t & 63;
    const int lrow = lane & 15;
    const int q = lane >> 4;
    unsigned barnum = 0;

    for (int l = 10; l >= 0; --l) {
        const int n = 1 << l;
        const int start = n - 1;
        const int startc = 2 * n - 1;
        const __hip_bfloat16* X = embB + (size_t)start * 256;
        const __hip_bfloat16* hp = hbuf + (size_t)startc * 256;
        const float* cp = cbuf + (size_t)startc * 256;
        __hip_bfloat16* ho = hbuf + (size_t)start * 256;
        float* co = cbuf + (size_t)start * 256;
        const int nmt = (n + 15) >> 4;       // 16-row m-tiles
        const int ntiles = nmt * 16;         // x 16 d-tiles
        // level 0: block 0 only (so root writes stay CU-local for write_out)
        const int wbase = (l == 0) ? ((bid == 0) ? w : ntiles) : (bid * 4 + w);
        const int wstep = (l == 0) ? 4 : TB * 4;

        for (int wt = wbase; wt < ntiles; wt += wstep) {
            // d-major: a block's 4 waves share dt -> B-fragments hit L1
            const int dt = wt / nmt;
            const int mt = wt - dt * nmt;
            const int m0 = mt * 16, d0 = dt * 16;
            floatx4 accS[3], accF[3];
            #pragma unroll
            for (int s = 0; s < 3; ++s) accS[s] = (floatx4){0.f, 0.f, 0.f, 0.f};
            #pragma unroll
            for (int p = 0; p < 3; ++p) accF[p] = (floatx4){0.f, 0.f, 0.f, 0.f};

            #pragma unroll
            for (int p = 0; p < 3; ++p) {
                const __hip_bfloat16* Ab = (p == 0) ? X : hp;
                const int astr = (p == 0) ? 256 : 512;
                const int aoff = (p == 0) ? 0 : (p - 1) * 256;
                #pragma unroll
                for (int kk = 0; kk < 8; ++kk) {
                    bf16x8 af = *(const bf16x8*)(Ab + (size_t)(m0 + lrow) * astr + aoff + kk * 32 + q * 8);
                    #pragma unroll
                    for (int s = 0; s < 4; ++s) {
                        bf16x8 bfr = *(const bf16x8*)(Wpack + (size_t)((p * 4 + s) * 256 + d0 + lrow) * 256 + kk * 32 + q * 8);
                        if (s < 3)
                            accS[s] = __builtin_amdgcn_mfma_f32_16x16x32_bf16(af, bfr, accS[s], 0, 0, 0);
                        else
                            accF[p] = __builtin_amdgcn_mfma_f32_16x16x32_bf16(af, bfr, accF[p], 0, 0, 0);
                    }
                }
            }

            const int d = d0 + lrow;
            const float bI = biasv[d];
            const float bO = biasv[256 + d];
            const float bU = biasv[512 + d];
            const float bF = biasv[768 + d];
            #pragma unroll
            for (int rr = 0; rr < 4; ++rr) {
                const int m = m0 + q * 4 + rr;
                if (m >= n) continue;
                float iv = sigf(accS[0][rr] + bI);
                float ov = sigf(accS[1][rr] + bO);
                float uv = tanhf(accS[2][rr] + bU);
                float fx = accF[0][rr];
                float fl = sigf(fx + accF[1][rr] + bF);
                float fr = sigf(fx + accF[2][rr] + bF);
                float c = iv * uv + fl * cp[(size_t)m * 512 + d]
                                  + fr * cp[(size_t)m * 512 + 256 + d];
                co[(size_t)m * 256 + d] = c;
                ho[(size_t)m * 256 + d] = __float2bfloat16(ov * tanhf(c));
            }
        }

        if (l > 0) {
            // ---- grid barrier: RELAXED spin + single acquire fence ----
            __syncthreads();
            ++barnum;
            if (t == 0) {
                unsigned v = __hip_atomic_fetch_add(&bar[0], 1, __ATOMIC_ACQ_REL,
                                                    __HIP_MEMORY_SCOPE_AGENT) + 1;
                if (v == barnum * (unsigned)TB) {
                    __hip_atomic_fetch_add(&bar[64], 1, __ATOMIC_RELEASE,
                                           __HIP_MEMORY_SCOPE_AGENT);
                } else {
                    while (__hip_atomic_load(&bar[64], __ATOMIC_RELAXED,
                                             __HIP_MEMORY_SCOPE_AGENT) < barnum)
                        __builtin_amdgcn_s_sleep(2);
                }
            }
            __syncthreads();
            __builtin_amdgcn_fence(__ATOMIC_ACQUIRE, "agent");
        }
    }

    if (bid == 0) {
        __syncthreads();
        out[t] = __bfloat162float(hbuf[t]);
        out[256 + t] = cbuf[t];
    }
}

extern "C" void kernel_launch(void* const* d_in, const int* in_sizes, int n_in,
                              void* d_out, int out_size, void* d_ws, size_t ws_size,
                              hipStream_t stream)
{
    const float* emb = (const float*)d_in[0];
    const float* Wi  = (const float*)d_in[1];
    const float* bi  = (const float*)d_in[2];
    const float* Ui  = (const float*)d_in[3];
    const float* Wo  = (const float*)d_in[4];
    const float* bo  = (const float*)d_in[5];
    const float* Uo  = (const float*)d_in[6];
    const float* Wu  = (const float*)d_in[7];
    const float* bu  = (const float*)d_in[8];
    const float* Uu  = (const float*)d_in[9];
    const float* Wf  = (const float*)d_in[10];
    const float* bf  = (const float*)d_in[11];
    const float* Uf  = (const float*)d_in[12];

    char* p = (char*)d_ws;
    __hip_bfloat16* Wpack = (__hip_bfloat16*)p;  p += (size_t)12 * 256 * 256 * 2;
    float* biasv          = (float*)p;           p += (size_t)4 * 256 * 4;
    __hip_bfloat16* embB  = (__hip_bfloat16*)p;  p += (size_t)65535 * 256 * 2;
    __hip_bfloat16* hbuf  = (__hip_bfloat16*)p;  p += (size_t)65535 * 256 * 2;
    float* cbuf           = (float*)p;           p += (size_t)65535 * 256 * 4;
    unsigned* bar         = (unsigned*)p;        p += 512;

    pack_weights<<<dim3(12, 256), 256, 0, stream>>>(Wi, bi, Ui, Wo, bo, Uo, Wu, bu, Uu, Wf, bf, Uf,
                                                    Wpack, biasv);
    convert_f32_bf16<<<(65535 * 256 / 4 + 255) / 256, 256, 0, stream>>>(emb, embB, 65535 * 256 / 4);

    // Leaves: level 15, n = 32768. 1 phase, 3 slots, c = i*u.
    {
        const int n = 32768, start = n - 1;
        fused_level<3, 1><<<dim3(4, n / 64), 256, 0, stream>>>(
            embB + (size_t)start * 256, nullptr, nullptr, Wpack, biasv,
            hbuf + (size_t)start * 256, cbuf + (size_t)start * 256, n);
    }
    // Big internal levels 14..11.
    for (int l = 14; l >= 11; --l) {
        const int n = 1 << l;
        const int start = n - 1;
        const int startc = 2 * n - 1;
        fused_level<4, 3><<<dim3(4, n / 64), 256, 0, stream>>>(
            embB + (size_t)start * 256,
            hbuf + (size_t)startc * 256,
            cbuf + (size_t)startc * 256,
            Wpack, biasv,
            hbuf + (size_t)start * 256, cbuf + (size_t)start * 256, n);
    }

    // Tail: levels 10..0 in one kernel + root write-out.
    hipMemsetAsync(bar, 0, 512, stream);
    tail_levels<<<TB, 256, 0, stream>>>(embB, hbuf, cbuf, Wpack, biasv, bar, (float*)d_out);
}

// Round 7
// 431.550 us; speedup vs baseline: 26.6892x; 1.3976x over previous
//
#include <hip/hip_runtime.h>
#include <hip/hip_bf16.h>
#include <cstdint>
#include <cstddef>

// NaryTreeLSTM bottom-up:
//  - gemm_zx: preZ[node][4*256] = x @ [Wi|Wo|Wu|Wf]^T + bias for tail nodes (0..2046)
//  - levels 15..11 (n>=2048): fused LDS-tiled MFMA kernel, one launch each
//  - levels 10..0: ONE 64-block kernel; U-weights LDS-stationary per d-tile,
//    A-fragments preloaded to VGPRs, relaxed-spin grid barrier between levels.
//
// Wpack[12][256][256] bf16: mats {Wi,Wo,Wu,Wf, Ui0,Uo0,Uu0,Uf0, Ui1,Uo1,Uu1,Uf1}
// biasv[4][256] fp32. h stored bf16, c fp32.
// f gates: f_l = sig(Wf x + bF + Uf0 h_l), f_r = sig(Wf x + bF + Uf1 h_r).

typedef __attribute__((ext_vector_type(8))) __bf16 bf16x8;
typedef __attribute__((ext_vector_type(4))) float floatx4;

#define TB 64   // tail grid: 16 d-tiles x 4 m-groups

__device__ __forceinline__ float sigf(float x) { return 1.0f / (1.0f + __expf(-x)); }

__device__ __forceinline__ void load_lds16(const void* g, void* l) {
    __builtin_amdgcn_global_load_lds(
        (const __attribute__((address_space(1))) unsigned int*)g,
        (__attribute__((address_space(3))) unsigned int*)l, 16, 0, 0);
}

__global__ void pack_weights(const float* __restrict__ Wi, const float* __restrict__ bi, const float* __restrict__ Ui,
                             const float* __restrict__ Wo, const float* __restrict__ bo, const float* __restrict__ Uo,
                             const float* __restrict__ Wu, const float* __restrict__ bu, const float* __restrict__ Uu,
                             const float* __restrict__ Wf, const float* __restrict__ bf, const float* __restrict__ Uf,
                             __hip_bfloat16* __restrict__ Wpack, float* __restrict__ biasv)
{
    int m = blockIdx.x;   // 0..11
    int d = blockIdx.y;   // 0..255
    int k = threadIdx.x;  // 0..255
    const float* tbl[12] = {Wi, Wo, Wu, Wf,
                            Ui, Uo, Uu, Uf,
                            Ui + 65536, Uo + 65536, Uu + 65536, Uf + 65536};
    Wpack[((size_t)m * 256 + d) * 256 + k] = __float2bfloat16(tbl[m][d * 256 + k]);
    if (m < 4 && k == 0) {
        const float* bt[4] = {bi, bo, bu, bf};
        biasv[m * 256 + d] = bt[m][d];
    }
}

__global__ void convert_f32_bf16(const float* __restrict__ in, __hip_bfloat16* __restrict__ out, int n4)
{
    int i = blockIdx.x * 256 + threadIdx.x;
    if (i >= n4) return;
    float4 v = ((const float4*)in)[i];
    __hip_bfloat16 tmp[4];
    tmp[0] = __float2bfloat16(v.x);
    tmp[1] = __float2bfloat16(v.y);
    tmp[2] = __float2bfloat16(v.z);
    tmp[3] = __float2bfloat16(v.w);
    *(ushort4*)(out + (size_t)i * 4) = *(const ushort4*)tmp;
}

// preZ[m][s*256+d] = sum_k embB[m][k]*Wpack[s*256+d][k] + biasv[s*256+d], m<M
__global__ __launch_bounds__(256) void gemm_zx(
    const __hip_bfloat16* __restrict__ embB,
    const __hip_bfloat16* __restrict__ Wpack,
    const float* __restrict__ biasv,
    float* __restrict__ preZ,
    int M)
{
    __shared__ __hip_bfloat16 sA[64 * 32];
    __shared__ __hip_bfloat16 sB[64 * 32];
    const int t = threadIdx.x;
    const int s = blockIdx.x >> 2;          // mat 0..3
    const int d0 = (blockIdx.x & 3) * 64;   // col block within mat
    const int bm0 = blockIdx.y * 64;
    const int lane = t & 63, w = t >> 6, lrow = lane & 15, q = lane >> 4;

    floatx4 acc[4];
    #pragma unroll
    for (int mt = 0; mt < 4; ++mt) acc[mt] = (floatx4){0.f, 0.f, 0.f, 0.f};

    for (int kk = 0; kk < 8; ++kk) {
        const int k0 = kk * 32;
        {
            int r = t >> 2, kc = t & 3;
            load_lds16(embB + (size_t)(bm0 + r) * 256 + k0 + kc * 8, &sA[t * 8]);
            load_lds16(Wpack + (size_t)(s * 256 + d0 + r) * 256 + k0 + kc * 8, &sB[t * 8]);
        }
        __syncthreads();
        bf16x8 af[4];
        #pragma unroll
        for (int mt = 0; mt < 4; ++mt)
            af[mt] = *(const bf16x8*)&sA[(mt * 16 + lrow) * 32 + q * 8];
        bf16x8 bfr = *(const bf16x8*)&sB[(w * 16 + lrow) * 32 + q * 8];
        #pragma unroll
        for (int mt = 0; mt < 4; ++mt)
            acc[mt] = __builtin_amdgcn_mfma_f32_16x16x32_bf16(af[mt], bfr, acc[mt], 0, 0, 0);
        __syncthreads();
    }

    const int d = d0 + w * 16 + lrow;
    const float bv = biasv[s * 256 + d];
    #pragma unroll
    for (int mt = 0; mt < 4; ++mt)
        #pragma unroll
        for (int rr = 0; rr < 4; ++rr) {
            int m = bm0 + mt * 16 + q * 4 + rr;
            if (m < M) preZ[(size_t)m * 1024 + s * 256 + d] = acc[mt][rr] + bv;
        }
}

// ---- big levels: fused LDS-tiled kernel (R4, unchanged) ------------------
template<int NS, int NP>
__global__ __launch_bounds__(256) void fused_level(
    const __hip_bfloat16* __restrict__ embX,
    const __hip_bfloat16* __restrict__ hprev,
    const float* __restrict__ cprev,
    const __hip_bfloat16* __restrict__ Wpack,
    const float* __restrict__ biasv,
    __hip_bfloat16* __restrict__ hout,
    float* __restrict__ cout,
    int M)
{
    __shared__ __hip_bfloat16 sA[64 * 32];
    __shared__ __hip_bfloat16 sB[NS * 64 * 32];
    const int t = threadIdx.x;
    const int dchunk = blockIdx.x;
    const int bm0 = blockIdx.y * 64;
    const int lane = t & 63;
    const int w = t >> 6;
    const int lrow = lane & 15;
    const int q = lane >> 4;

    floatx4 accS[3][4];
    floatx4 accF[NP][4];
    #pragma unroll
    for (int s = 0; s < 3; ++s)
        #pragma unroll
        for (int mt = 0; mt < 4; ++mt) accS[s][mt] = (floatx4){0.f, 0.f, 0.f, 0.f};
    #pragma unroll
    for (int p = 0; p < NP; ++p)
        #pragma unroll
        for (int mt = 0; mt < 4; ++mt) accF[p][mt] = (floatx4){0.f, 0.f, 0.f, 0.f};

    #pragma unroll
    for (int p = 0; p < NP; ++p) {
        const __hip_bfloat16* Abase = (p == 0) ? embX : hprev;
        const int astride = (p == 0) ? 256 : 512;
        const int aoff = (p == 0) ? 0 : (p - 1) * 256;
        for (int kk = 0; kk < 8; ++kk) {
            const int k0 = kk * 32;
            {
                int r = t >> 2, kc = t & 3;
                load_lds16(Abase + (size_t)(bm0 + r) * astride + aoff + k0 + kc * 8,
                           &sA[t * 8]);
            }
            #pragma unroll
            for (int rep = 0; rep < NS; ++rep) {
                int cid = rep * 256 + t;
                int row = cid >> 2, kc = cid & 3;
                int s = row >> 6, r = row & 63;
                load_lds16(Wpack + (size_t)((p * 4 + s) * 256 + dchunk * 64 + r) * 256 + k0 + kc * 8,
                           &sB[cid * 8]);
            }
            __syncthreads();

            bf16x8 af[4];
            #pragma unroll
            for (int mt = 0; mt < 4; ++mt)
                af[mt] = *(const bf16x8*)&sA[(mt * 16 + lrow) * 32 + q * 8];
            #pragma unroll
            for (int s = 0; s < NS; ++s) {
                bf16x8 bfrag = *(const bf16x8*)&sB[(s * 64 + w * 16 + lrow) * 32 + q * 8];
                if (s < 3) {
                    #pragma unroll
                    for (int mt = 0; mt < 4; ++mt)
                        accS[s][mt] = __builtin_amdgcn_mfma_f32_16x16x32_bf16(af[mt], bfrag, accS[s][mt], 0, 0, 0);
                } else {
                    #pragma unroll
                    for (int mt = 0; mt < 4; ++mt)
                        accF[p][mt] = __builtin_amdgcn_mfma_f32_16x16x32_bf16(af[mt], bfrag, accF[p][mt], 0, 0, 0);
                }
            }
            __syncthreads();
        }
    }

    const int d = dchunk * 64 + w * 16 + lrow;
    const float bI = biasv[d];
    const float bO = biasv[256 + d];
    const float bU = biasv[512 + d];
    const float bF = (NS == 4) ? biasv[768 + d] : 0.0f;
    #pragma unroll
    for (int mt = 0; mt < 4; ++mt) {
        #pragma unroll
        for (int rr = 0; rr < 4; ++rr) {
            const int m = bm0 + mt * 16 + q * 4 + rr;
            if (m >= M) continue;
            float iv = sigf(accS[0][mt][rr] + bI);
            float ov = sigf(accS[1][mt][rr] + bO);
            float uv = tanhf(accS[2][mt][rr] + bU);
            float c;
            if (NS == 4) {
                float fx = accF[0][mt][rr];
                float fl = sigf(fx + accF[NP >= 2 ? 1 : 0][mt][rr] + bF);
                float fr = sigf(fx + accF[NP >= 3 ? 2 : 0][mt][rr] + bF);
                c = iv * uv + fl * cprev[(size_t)m * 512 + d]
                            + fr * cprev[(size_t)m * 512 + 256 + d];
            } else {
                c = iv * uv;
            }
            cout[(size_t)m * 256 + d] = c;
            hout[(size_t)m * 256 + d] = __float2bfloat16(ov * tanhf(c));
        }
    }
}

// ---- tail: levels 10..0, U-weights LDS-stationary ------------------------
__global__ __launch_bounds__(256) void tail_levels(
    __hip_bfloat16* __restrict__ hbuf, float* __restrict__ cbuf,
    const __hip_bfloat16* __restrict__ Wpack,
    const float* __restrict__ preZ,
    unsigned* __restrict__ bar, float* __restrict__ out)
{
    __shared__ __hip_bfloat16 sB[8 * 16 * 256];   // 64 KB: U mats for this d-tile
    const int bid = blockIdx.x;
    const int t = threadIdx.x;
    const int dt = bid & 15;     // d-tile
    const int g = bid >> 4;      // m-group 0..3
    const int w = t >> 6, lane = t & 63, lrow = lane & 15, q = lane >> 4;

    // Stage U mats 4..11, rows dt*16..+16, once (survives inter-level fences).
    for (int rnd = 0; rnd < 16; ++rnd) {
        int C = rnd * 256 + t;               // chunk 0..4095
        int q8k = C & 31, r = (C >> 5) & 15, m8 = C >> 9;
        load_lds16(Wpack + (size_t)((4 + m8) * 256 + dt * 16 + r) * 256 + q8k * 8,
                   &sB[(size_t)C * 8]);
    }
    __syncthreads();

    const int d = dt * 16 + lrow;
    unsigned barnum = 0;

    for (int l = 10; l >= 0; --l) {
        const int n = 1 << l;
        const int start = n - 1;
        const int startc = 2 * n - 1;
        const __hip_bfloat16* hp = hbuf + (size_t)startc * 256;
        const float* cp = cbuf + (size_t)startc * 256;
        __hip_bfloat16* ho = hbuf + (size_t)start * 256;
        float* co = cbuf + (size_t)start * 256;
        const int nmt = (n + 15) >> 4;

        for (int mt = g * 4 + w; mt < nmt; mt += 16) {
            const int m0 = mt * 16;
            // Preload A fragments (children h): 16 independent loads.
            bf16x8 af[2][8];
            #pragma unroll
            for (int p = 0; p < 2; ++p)
                #pragma unroll
                for (int kk = 0; kk < 8; ++kk)
                    af[p][kk] = *(const bf16x8*)(hp + (size_t)(m0 + lrow) * 512 + p * 256 + kk * 32 + q * 8);
            // Preload z (bias folded) and child c.
            float zi[4][4], clr[2][4];
            #pragma unroll
            for (int rr = 0; rr < 4; ++rr) {
                int m = m0 + q * 4 + rr;
                #pragma unroll
                for (int s = 0; s < 4; ++s)
                    zi[s][rr] = preZ[(size_t)(start + m) * 1024 + s * 256 + d];
                clr[0][rr] = cp[(size_t)m * 512 + d];
                clr[1][rr] = cp[(size_t)m * 512 + 256 + d];
            }

            floatx4 accS[3], accF1, accF2;
            #pragma unroll
            for (int s = 0; s < 3; ++s)
                accS[s] = (floatx4){zi[s][0], zi[s][1], zi[s][2], zi[s][3]};
            accF1 = (floatx4){0.f, 0.f, 0.f, 0.f};
            accF2 = (floatx4){0.f, 0.f, 0.f, 0.f};

            #pragma unroll
            for (int p = 0; p < 2; ++p)
                #pragma unroll
                for (int kk = 0; kk < 8; ++kk)
                    #pragma unroll
                    for (int s = 0; s < 4; ++s) {
                        bf16x8 bfr = *(const bf16x8*)&sB[((p * 4 + s) * 16 + lrow) * 256 + kk * 32 + q * 8];
                        if (s < 3)
                            accS[s] = __builtin_amdgcn_mfma_f32_16x16x32_bf16(af[p][kk], bfr, accS[s], 0, 0, 0);
                        else if (p == 0)
                            accF1 = __builtin_amdgcn_mfma_f32_16x16x32_bf16(af[p][kk], bfr, accF1, 0, 0, 0);
                        else
                            accF2 = __builtin_amdgcn_mfma_f32_16x16x32_bf16(af[p][kk], bfr, accF2, 0, 0, 0);
                    }

            #pragma unroll
            for (int rr = 0; rr < 4; ++rr) {
                int m = m0 + q * 4 + rr;
                if (m >= n) continue;
                float iv = sigf(accS[0][rr]);
                float ov = sigf(accS[1][rr]);
                float uv = tanhf(accS[2][rr]);
                float fx = zi[3][rr];
                float fl = sigf(fx + accF1[rr]);
                float fr = sigf(fx + accF2[rr]);
                float c = iv * uv + fl * clr[0][rr] + fr * clr[1][rr];
                float hv = ov * tanhf(c);
                if (l == 0) {
                    out[d] = hv;           // root h, fp32
                    out[256 + d] = c;      // root c
                } else {
                    co[(size_t)m * 256 + d] = c;
                    ho[(size_t)m * 256 + d] = __float2bfloat16(hv);
                }
            }
        }

        if (l > 0) {
            // Grid barrier: relaxed spin + single acquire fence (R6-proven).
            __syncthreads();
            ++barnum;
            if (t == 0) {
                unsigned v = __hip_atomic_fetch_add(&bar[0], 1, __ATOMIC_ACQ_REL,
                                                    __HIP_MEMORY_SCOPE_AGENT) + 1;
                if (v == barnum * (unsigned)TB) {
                    __hip_atomic_fetch_add(&bar[64], 1, __ATOMIC_RELEASE,
                                           __HIP_MEMORY_SCOPE_AGENT);
                } else {
                    while (__hip_atomic_load(&bar[64], __ATOMIC_RELAXED,
                                             __HIP_MEMORY_SCOPE_AGENT) < barnum)
                        __builtin_amdgcn_s_sleep(1);
                }
            }
            __syncthreads();
            __builtin_amdgcn_fence(__ATOMIC_ACQUIRE, "agent");
        }
    }
}

extern "C" void kernel_launch(void* const* d_in, const int* in_sizes, int n_in,
                              void* d_out, int out_size, void* d_ws, size_t ws_size,
                              hipStream_t stream)
{
    const float* emb = (const float*)d_in[0];
    const float* Wi  = (const float*)d_in[1];
    const float* bi  = (const float*)d_in[2];
    const float* Ui  = (const float*)d_in[3];
    const float* Wo  = (const float*)d_in[4];
    const float* bo  = (const float*)d_in[5];
    const float* Uo  = (const float*)d_in[6];
    const float* Wu  = (const float*)d_in[7];
    const float* bu  = (const float*)d_in[8];
    const float* Uu  = (const float*)d_in[9];
    const float* Wf  = (const float*)d_in[10];
    const float* bf  = (const float*)d_in[11];
    const float* Uf  = (const float*)d_in[12];

    char* p = (char*)d_ws;
    __hip_bfloat16* Wpack = (__hip_bfloat16*)p;  p += (size_t)12 * 256 * 256 * 2;
    float* biasv          = (float*)p;           p += (size_t)4 * 256 * 4;
    __hip_bfloat16* embB  = (__hip_bfloat16*)p;  p += (size_t)65535 * 256 * 2;
    __hip_bfloat16* hbuf  = (__hip_bfloat16*)p;  p += (size_t)65535 * 256 * 2;
    float* cbuf           = (float*)p;           p += (size_t)65535 * 256 * 4;
    float* preZ           = (float*)p;           p += (size_t)2047 * 1024 * 4;
    unsigned* bar         = (unsigned*)p;        p += 512;

    pack_weights<<<dim3(12, 256), 256, 0, stream>>>(Wi, bi, Ui, Wo, bo, Uo, Wu, bu, Uu, Wf, bf, Uf,
                                                    Wpack, biasv);
    convert_f32_bf16<<<(65535 * 256 / 4 + 255) / 256, 256, 0, stream>>>(emb, embB, 65535 * 256 / 4);

    // x-phase pre-GEMM for tail nodes (levels 10..0 = nodes 0..2046).
    gemm_zx<<<dim3(16, 32), 256, 0, stream>>>(embB, Wpack, biasv, preZ, 2047);

    // Leaves: level 15, n = 32768. 1 phase, 3 slots, c = i*u.
    {
        const int n = 32768, start = n - 1;
        fused_level<3, 1><<<dim3(4, n / 64), 256, 0, stream>>>(
            embB + (size_t)start * 256, nullptr, nullptr, Wpack, biasv,
            hbuf + (size_t)start * 256, cbuf + (size_t)start * 256, n);
    }
    // Big internal levels 14..11.
    for (int l = 14; l >= 11; --l) {
        const int n = 1 << l;
        const int start = n - 1;
        const int startc = 2 * n - 1;
        fused_level<4, 3><<<dim3(4, n / 64), 256, 0, stream>>>(
            embB + (size_t)start * 256,
            hbuf + (size_t)startc * 256,
            cbuf + (size_t)startc * 256,
            Wpack, biasv,
            hbuf + (size_t)start * 256, cbuf + (size_t)start * 256, n);
    }

    // Tail: levels 10..0 in one kernel; writes root h,c to out directly.
    hipMemsetAsync(bar, 0, 512, stream);
    tail_levels<<<TB, 256, 0, stream>>>(hbuf, cbuf, Wpack, preZ, bar, (float*)d_out);
}